// Round 3
// baseline (1070.519 us; speedup 1.0000x reference)
//
#include <hip/hip_runtime.h>

#define DEV __device__ __forceinline__

// ---------------- workspace layout (float offsets), < 7.41M floats = 29.7 MB ----------
// phi1 region [0 .. 6,291,456) is dead after k_fused1; phi2/phi3/final reuse it.
#define W_PHI1L 0u
#define W_PHI1C 3145728u
// reuse of phi1 region after stage 1:
#define W_PHI2L 0u          // 1,310,720
#define W_PHI2C 1310720u    // 1,310,720  -> 2,621,440
#define W_PHI3L 2621440u    // 131,072    -> 2,752,512
#define W_PHI3C 2752512u    // 131,072    -> 2,883,584
#define W_MF    2883584u    // 131,072    -> 3,014,656
#define W_PHIF  3014656u    // 32,768     -> 3,047,424
// persistent region:
#define W_LY    6291456u    // 131,072
#define W_CY    6422528u    // 524,288
#define W_SCL   6946816u    // 256
#define W_SHL   6947072u    // 256
#define W_SCC   6947328u    // 1024
#define W_SHC   6948352u    // 1024
#define W_LR1L  6949376u    // 65,536
#define W_LR1C  7014912u    // 262,144
#define W_LR2L  7277056u    // 16,384
#define W_LR2C  7293440u    // 16,384
#define W_LR3L  7309824u    // 4,096
#define W_LR3C  7313920u    // 4,096
#define W_LO2   7318016u    // 32,768
#define W_CO2   7350784u    // 32,768
#define W_SC2   7383552u    // 64
#define W_SH2   7383616u    // 64
#define W_LO3   7383680u    // 8,192
#define W_CO3   7391872u    // 8,192

// =====================================================================================
// All-register fused MPS: one WG (256 thr) per patch. No LDS, no __syncthreads.
// Lane (eg=t&31, bg=t>>5) holds, for b = bg*4+a (a<4):
//   M_l[b][i=eg>>1][j=(eg&1)*8+e]  in acc[a][e]   (cols flat e' = eg*8+e = i*16+j)
//   v[b][i_lane=eg>>1]             in vscal[a]
// Chain step: pw = vscal*acc; butterfly-reduce over i (xor 2,4,8,16) -> w[b][j=h*8+e]
// everywhere; next vscal[a] = w[b][eg>>1] via xor-1 half-swap + 3-level cndmask select.
// Epilogue: out[b][p][o=eg>>1] = sum_i w[b][i]*labRB[i][o], pair-reduced with xor-1.
// =====================================================================================
template<int L, int F>
DEV void mps_reg(const float* __restrict__ phiP, const float* __restrict__ corP,
                 const float* __restrict__ labRBp, float* __restrict__ outp,
                 int P, int p)
{
    const int t  = threadIdx.x;
    const int eg = t & 31, bg = t >> 5;
    const int h  = eg & 1;
    const int hstar = eg >> 4;          // needed half for next-v select
    const int estar = (eg >> 1) & 7;    // needed element within half
    float vscal[4] = {0.25f, 0.25f, 0.25f, 0.25f};   // LB = D^-0.5
    float pw[4][8];

    #pragma unroll 1
    for (int l = 0; l < L; ++l) {
        const float* __restrict__ cPL = corP + (size_t)l * F * 256 + eg * 8;
        const float* __restrict__ pPL = phiP + (size_t)l * F * 32  + bg * 4;
        float acc[4][8];
        #pragma unroll
        for (int a = 0; a < 4; ++a)
            #pragma unroll
            for (int e = 0; e < 8; ++e) acc[a][e] = 0.f;
        #pragma unroll 4
        for (int f = 0; f < F; ++f) {
            float4 c0 = *reinterpret_cast<const float4*>(cPL + f * 256);
            float4 c1 = *reinterpret_cast<const float4*>(cPL + f * 256 + 4);
            float4 pb = *reinterpret_cast<const float4*>(pPL + f * 32);
            float ce[8] = {c0.x, c0.y, c0.z, c0.w, c1.x, c1.y, c1.z, c1.w};
            float pv[4] = {pb.x, pb.y, pb.z, pb.w};
            #pragma unroll
            for (int a = 0; a < 4; ++a)
                #pragma unroll
                for (int e = 0; e < 8; ++e) acc[a][e] = fmaf(pv[a], ce[e], acc[a][e]);
        }
        // pw[a][e] = v[b][i_lane] * M[b][i_lane][h*8+e]
        #pragma unroll
        for (int a = 0; a < 4; ++a)
            #pragma unroll
            for (int e = 0; e < 8; ++e) pw[a][e] = vscal[a] * acc[a][e];
        // butterfly over i (lanes differing in eg bits 1..4; h, bg preserved)
        #pragma unroll
        for (int st = 0; st < 4; ++st) {
            const int mask = 2 << st;
            #pragma unroll
            for (int a = 0; a < 4; ++a)
                #pragma unroll
                for (int e = 0; e < 8; ++e)
                    pw[a][e] += __shfl_xor(pw[a][e], mask);
        }
        if (l != L - 1) {
            // next vscal[a] = w[b][eg>>1]
            #pragma unroll
            for (int a = 0; a < 4; ++a) {
                float sel[8];
                #pragma unroll
                for (int e = 0; e < 8; ++e) {
                    float oth = __shfl_xor(pw[a][e], 1);
                    sel[e] = (h == hstar) ? pw[a][e] : oth;
                }
                float y0 = (estar & 4) ? sel[4] : sel[0];
                float y1 = (estar & 4) ? sel[5] : sel[1];
                float y2 = (estar & 4) ? sel[6] : sel[2];
                float y3 = (estar & 4) ? sel[7] : sel[3];
                float z0 = (estar & 2) ? y2 : y0;
                float z1 = (estar & 2) ? y3 : y1;
                vscal[a] = (estar & 1) ? z1 : z0;
            }
        }
    }
    // epilogue: out[b][o] = sum_i v_final[b][i] * labRB[i][o], o = eg>>1
    const int o = eg >> 1;
    float part[4] = {0.f, 0.f, 0.f, 0.f};
    #pragma unroll
    for (int e = 0; e < 8; ++e) {
        float lv = labRBp[(h * 8 + e) * 16 + o];
        #pragma unroll
        for (int a = 0; a < 4; ++a) part[a] = fmaf(pw[a][e], lv, part[a]);
    }
    #pragma unroll
    for (int a = 0; a < 4; ++a) part[a] += __shfl_xor(part[a], 1);
    if (h == 0) {
        #pragma unroll
        for (int a = 0; a < 4; ++a)
            outp[((size_t)(bg * 4 + a) * P + p) * 16 + o] = part[a];
    }
}

__global__ __launch_bounds__(256) void k_fused1(const float* __restrict__ phi1L,
    const float* __restrict__ phi1C, const float* __restrict__ l1c,
    const float* __restrict__ c1c, const float* __restrict__ lr1L,
    const float* __restrict__ lr1C, float* __restrict__ ly, float* __restrict__ cy)
{
    int wg = blockIdx.x;
    if (wg < 256) {
        int p = wg;
        mps_reg<4, 96>(phi1L + (size_t)p * 12288, l1c + (size_t)p * 98304,
                       lr1L + (size_t)p * 256, ly, 256, p);
    } else {
        int p = wg - 256;
        mps_reg<3, 32>(phi1C + (size_t)p * 3072, c1c + (size_t)p * 24576,
                       lr1C + (size_t)p * 256, cy, 1024, p);
    }
}

__global__ __launch_bounds__(256) void k_fused2(const float* __restrict__ phi2L,
    const float* __restrict__ phi2C, const float* __restrict__ l2c,
    const float* __restrict__ c2c, const float* __restrict__ lr2L,
    const float* __restrict__ lr2C, float* __restrict__ lo2, float* __restrict__ co2)
{
    int wg = blockIdx.x;
    if (wg < 64) {
        int p = wg;
        mps_reg<20, 32>(phi2L + (size_t)p * 20480, l2c + (size_t)p * 163840,
                        lr2L + (size_t)p * 256, lo2, 64, p);
    } else {
        int p = wg - 64;
        mps_reg<16, 40>(phi2C + (size_t)p * 20480, c2c + (size_t)p * 163840,
                        lr2C + (size_t)p * 256, co2, 64, p);
    }
}

__global__ __launch_bounds__(256) void k_fused3(const float* __restrict__ phi3L,
    const float* __restrict__ phi3C, const float* __restrict__ l3c,
    const float* __restrict__ c3c, const float* __restrict__ lr3L,
    const float* __restrict__ lr3C, float* __restrict__ lo3, float* __restrict__ co3)
{
    int wg = blockIdx.x;
    if (wg < 16) {
        int p = wg;
        mps_reg<4, 64>(phi3L + (size_t)p * 8192, l3c + (size_t)p * 65536,
                       lr3L + (size_t)p * 256, lo3, 16, p);
    } else {
        int p = wg - 16;
        mps_reg<32, 8>(phi3C + (size_t)p * 8192, c3c + (size_t)p * 65536,
                       lr3C + (size_t)p * 256, co3, 16, p);
    }
}

// Precontract ALL labels with RB: labRB[p][i][o] = 0.25 * sum_j lab[p][i][o][j]
__global__ __launch_bounds__(256) void k_labRB(const float* __restrict__ l1l,
    const float* __restrict__ c1l, const float* __restrict__ l2l,
    const float* __restrict__ c2l, const float* __restrict__ l3l,
    const float* __restrict__ c3l, float* __restrict__ ws)
{
    int idx = blockIdx.x * 256 + threadIdx.x;   // < 368,640
    const float* src; float* dst; int e;
    if (idx < 65536)       { src = l1l; dst = ws + W_LR1L; e = idx; }
    else if (idx < 327680) { src = c1l; dst = ws + W_LR1C; e = idx - 65536; }
    else if (idx < 344064) { src = l2l; dst = ws + W_LR2L; e = idx - 327680; }
    else if (idx < 360448) { src = c2l; dst = ws + W_LR2C; e = idx - 344064; }
    else if (idx < 364544) { src = l3l; dst = ws + W_LR3L; e = idx - 360448; }
    else                   { src = c3l; dst = ws + W_LR3C; e = idx - 364544; }
    const float* lp = src + (size_t)e * 16;
    float s = 0.f;
    #pragma unroll
    for (int jj = 0; jj < 16; ++jj) s += lp[jj];
    dst[e] = s * 0.25f;
}

// =====================================================================================
// Stage-1 phi gather: each thread gathers once, writes v and 1-v.
// =====================================================================================
__global__ __launch_bounds__(256) void k_phi1(const float* __restrict__ x,
                                              float* __restrict__ phiL,
                                              float* __restrict__ phiC)
{
    int idx = blockIdx.x * 256 + threadIdx.x;   // < 3,145,728
    if (idx < 1572864) {                        // LoTe: (p,l,C<48,b)
        int b = idx & 31;
        int r = idx >> 5;
        int C = r % 48; r /= 48;
        int l = r & 3;  int p = r >> 2;
        int flat = C * 1024 + p * 4 + l;        // over [3,8,8,16,16]
        int c = flat >> 14, hh = (flat >> 11) & 7, w = (flat >> 8) & 7;
        int i = (flat >> 4) & 15, j = flat & 15;
        float v = x[b * 49152 + c * 16384 + (hh * 16 + i) * 128 + (w * 16 + j)];
        int base = ((p * 4 + l) * 96 + C) * 32 + b;
        phiL[base] = v;
        phiL[base + 48 * 32] = 1.0f - v;
    } else {                                    // conv: (p,l,C<16,b)
        int k = idx - 1572864;
        int b = k & 31;
        int r = k >> 5;
        int C = r & 15; r >>= 4;
        int l = r % 3;  int p = r / 3;
        int flat = C * 3072 + p * 3 + l;        // over [3,32,32,4,4]
        int c = flat >> 14, hb = (flat >> 9) & 31, wb = (flat >> 4) & 31;
        int i = (flat >> 2) & 3, j = flat & 3;
        float v = x[b * 49152 + c * 16384 + (hb * 4 + i) * 128 + (wb * 4 + j)];
        int base = ((p * 3 + l) * 32 + C) * 32 + b;
        phiC[base] = v;
        phiC[base + 16 * 32] = 1.0f - v;
    }
}

// =====================================================================================
// BN stats -> per-channel scale/shift
// =====================================================================================
__global__ __launch_bounds__(64) void k_bn1(const float* __restrict__ ly, const float* __restrict__ cy,
    const float* __restrict__ g1, const float* __restrict__ b1,
    const float* __restrict__ gc1, const float* __restrict__ bc1,
    float* __restrict__ scL, float* __restrict__ shL,
    float* __restrict__ scC, float* __restrict__ shC)
{
    int ch = blockIdx.x, t = threadIdx.x;
    const float *src, *g, *bb; float *sc, *sh; int cc, stride;
    if (ch < 256) { src = ly; g = g1;  bb = b1;  sc = scL; sh = shL; cc = ch;       stride = 4096;  }
    else          { src = cy; g = gc1; bb = bc1; sc = scC; sh = shC; cc = ch - 256; stride = 16384; }
    int o = t & 15, b0 = t >> 4;
    float s = 0.f, sq = 0.f;
    for (int b = b0; b < 32; b += 4) { float v = src[b * stride + cc * 16 + o]; s += v; sq += v * v; }
    for (int off = 32; off > 0; off >>= 1) { s += __shfl_down(s, off); sq += __shfl_down(sq, off); }
    if (t == 0) {
        float mean = s * (1.f / 512.f);
        float var  = sq * (1.f / 512.f) - mean * mean;
        float scale = rsqrtf(var + 1e-5f) * g[cc];
        sc[cc] = scale; sh[cc] = bb[cc] - mean * scale;
    }
}

DEV float comb_val(const float* __restrict__ ly, const float* __restrict__ cy,
                   const float* __restrict__ scL, const float* __restrict__ shL,
                   const float* __restrict__ scC, const float* __restrict__ shC,
                   int b, int ch, int p, int a)
{
    if (a < 4) {
        int flat = p * 4 + a;
        int hb = flat >> 7, wb = (flat >> 6) & 1, i = (flat >> 3) & 7, j = flat & 7;
        int P1 = ch * 16 + hb * 8 + i;
        int s  = wb * 8 + j;
        return ly[b * 4096 + P1 * 16 + s] * scL[P1] + shL[P1];
    } else {
        int d = a - 4;
        int hb = p >> 3, wb = p & 7;
        int i = ch >> 2, j = ch & 3;
        int r = hb * 4 + i, c = wb * 4 + j;
        int P1 = d * 64 + r * 2 + (c >> 4);
        int o  = c & 15;
        return cy[b * 16384 + P1 * 16 + o] * scC[P1] + shC[P1];
    }
}

__global__ __launch_bounds__(256) void k_phi2(const float* __restrict__ ly, const float* __restrict__ cy,
    const float* __restrict__ scL, const float* __restrict__ shL,
    const float* __restrict__ scC, const float* __restrict__ shC,
    float* __restrict__ phi2L, float* __restrict__ phi2C)
{
    int idx = blockIdx.x * 256 + threadIdx.x;   // < 1,310,720
    if (idx < 655360) {                         // phi2L: (p,l<20,ch<16,b)
        int b = idx & 31;
        int r = idx >> 5;
        int ch = r & 15; r >>= 4;
        int l = r % 20; int p = r / 20;
        float v = comb_val(ly, cy, scL, shL, scC, shC, b, ch, p, l);
        int base = ((p * 20 + l) * 32 + ch) * 32 + b;
        phi2L[base] = v;
        phi2L[base + 512] = 1.0f - v;
    } else {                                    // phi2C: (p,l<16,a<20,b)
        int k = idx - 655360;
        int b = k & 31;
        int r = k >> 5;
        int a = r % 20; r /= 20;
        int l = r & 15; int p = r >> 4;
        float v = comb_val(ly, cy, scL, shL, scC, shC, b, l, p, a);
        int base = ((p * 16 + l) * 40 + a) * 32 + b;
        phi2C[base] = v;
        phi2C[base + 640] = 1.0f - v;
    }
}

__global__ __launch_bounds__(64) void k_bn2(const float* __restrict__ lo2, const float* __restrict__ co2,
    const float* __restrict__ g2, const float* __restrict__ b2,
    float* __restrict__ sc2, float* __restrict__ sh2)
{
    int ch = blockIdx.x, t = threadIdx.x;
    int o = t & 31, b0 = t >> 5;
    float s = 0.f, sq = 0.f;
    for (int b = b0; b < 32; b += 2) {
        float v = (o < 16) ? lo2[b * 1024 + ch * 16 + o] : co2[b * 1024 + ch * 16 + (o - 16)];
        s += v; sq += v * v;
    }
    for (int off = 32; off > 0; off >>= 1) { s += __shfl_down(s, off); sq += __shfl_down(sq, off); }
    if (t == 0) {
        float mean = s * (1.f / 1024.f);
        float var  = sq * (1.f / 1024.f) - mean * mean;
        float scale = rsqrtf(var + 1e-5f) * g2[ch];
        sc2[ch] = scale; sh2[ch] = b2[ch] - mean * scale;
    }
}

DEV float grid_val(const float* __restrict__ lo2, const float* __restrict__ co2,
                   const float* __restrict__ sc2, const float* __restrict__ sh2,
                   int b, int ch, int r, int c)
{
    int rc = r * 8 + c;
    int p = ch * 2 + (rc >> 5);
    int o = rc & 31;
    float v = (o < 16) ? lo2[b * 1024 + p * 16 + o] : co2[b * 1024 + p * 16 + (o - 16)];
    return v * sc2[p] + sh2[p];
}

__global__ __launch_bounds__(256) void k_phi3(const float* __restrict__ lo2, const float* __restrict__ co2,
    const float* __restrict__ sc2, const float* __restrict__ sh2,
    float* __restrict__ phi3L, float* __restrict__ phi3C)
{
    int idx = blockIdx.x * 256 + threadIdx.x;   // < 131,072
    if (idx < 65536) {                          // phi3L: (p,l<4,ch<32,b)
        int b = idx & 31;
        int r = idx >> 5;
        int ch = r & 31; r >>= 5;
        int l = r & 3;  int p = r >> 2;
        int flat = p * 4 + l;
        int hb = flat >> 5, wb = (flat >> 4) & 1, i = (flat >> 2) & 3, j = flat & 3;
        float v = grid_val(lo2, co2, sc2, sh2, b, ch, hb * 4 + i, wb * 4 + j);
        int base = ((p * 4 + l) * 64 + ch) * 32 + b;
        phi3L[base] = v;
        phi3L[base + 1024] = 1.0f - v;
    } else {                                    // phi3C: (p,l<32,a<4,b)
        int k = idx - 65536;
        int b = k & 31;
        int r = k >> 5;
        int a = r & 3;  r >>= 2;
        int l = r & 31; int p = r >> 5;
        int c32 = a * 8 + (p >> 1);
        int hb = (p & 1) * 2 + (l >> 4);
        int wb = (l >> 2) & 3;
        int i = (l >> 1) & 1, j = l & 1;
        float v = grid_val(lo2, co2, sc2, sh2, b, c32, hb * 2 + i, wb * 2 + j);
        int base = ((p * 32 + l) * 8 + a) * 32 + b;
        phi3C[base] = v;
        phi3C[base + 128] = 1.0f - v;
    }
}

__global__ __launch_bounds__(256) void k_bn3_phiF(const float* __restrict__ lo3, const float* __restrict__ co3,
    const float* __restrict__ g3, const float* __restrict__ b3,
    float* __restrict__ phiF)
{
    __shared__ float sc3[16], sh3[16];
    int t = threadIdx.x;
    int ch = t >> 4, r = t & 15;
    float s = 0.f, sq = 0.f;
    for (int k2 = 0; k2 < 64; ++k2) {
        int v = r * 64 + k2;
        int b = v >> 5, o = v & 31;
        float x = (o < 16) ? lo3[b * 256 + ch * 16 + o] : co3[b * 256 + ch * 16 + (o - 16)];
        s += x; sq += x * x;
    }
    for (int off = 8; off > 0; off >>= 1) { s += __shfl_down(s, off, 16); sq += __shfl_down(sq, off, 16); }
    if (r == 0) {
        float mean = s * (1.f / 1024.f);
        float var  = sq * (1.f / 1024.f) - mean * mean;
        float scale = rsqrtf(var + 1e-5f) * g3[ch];
        sc3[ch] = scale; sh3[ch] = b3[ch] - mean * scale;
    }
    __syncthreads();
    for (int k = t; k < 32768; k += 256) {
        int b = k & 31;
        int rr = k >> 5;
        int f = rr & 63;
        int l = rr >> 6;
        int o = (f < 32) ? f : f - 32;
        float raw = (o < 16) ? lo3[b * 256 + l * 16 + o] : co3[b * 256 + l * 16 + (o - 16)];
        float v = raw * sc3[l] + sh3[l];
        phiF[k] = (f < 32) ? v : 1.0f - v;
    }
}

__global__ __launch_bounds__(256) void k_mpsF_build(const float* __restrict__ phiF,
    const float* __restrict__ fc, float* __restrict__ MF)
{
    int l = blockIdx.x;
    int t = threadIdx.x, eg = t & 31, bg = t >> 5;
    const float* __restrict__ cPL = fc + (size_t)l * 16384 + eg * 8;
    const float* __restrict__ pPL = phiF + (size_t)l * 2048 + bg * 4;
    float acc[4][8];
    #pragma unroll
    for (int a = 0; a < 4; ++a)
        #pragma unroll
        for (int e = 0; e < 8; ++e) acc[a][e] = 0.f;
    #pragma unroll 2
    for (int f = 0; f < 64; ++f) {
        float ce[8], pb[4];
        #pragma unroll
        for (int e = 0; e < 8; ++e) ce[e] = cPL[f * 256 + e];
        #pragma unroll
        for (int a = 0; a < 4; ++a) pb[a] = pPL[f * 32 + a];
        #pragma unroll
        for (int a = 0; a < 4; ++a)
            #pragma unroll
            for (int e = 0; e < 8; ++e) acc[a][e] = fmaf(pb[a], ce[e], acc[a][e]);
    }
    #pragma unroll
    for (int a = 0; a < 4; ++a)
        #pragma unroll
        for (int e = 0; e < 8; ++e)
            MF[(size_t)(l * 32 + bg * 4 + a) * 256 + eg * 8 + e] = acc[a][e];
}

__global__ __launch_bounds__(256) void k_mpsF_chain(const float* __restrict__ MF,
    const float* __restrict__ fl, float* __restrict__ out)
{
    __shared__ float Msh[32 * 264];
    __shared__ float vsh[32 * 17];
    __shared__ float lsh[16 * 17];
    int t = threadIdx.x;
    for (int k = t; k < 512; k += 256) vsh[(k >> 4) * 17 + (k & 15)] = 0.25f;
    for (int l = 0; l < 16; ++l) {
        __syncthreads();
        for (int k = t; k < 8192; k += 256) {
            int b = k >> 8, e = k & 255;
            Msh[b * 264 + e] = MF[l * 8192 + k];
        }
        __syncthreads();
        float wv[2];
        #pragma unroll
        for (int q = 0; q < 2; ++q) {
            int k = t + q * 256;
            int b = k >> 4, j = k & 15;
            float s = 0.f;
            #pragma unroll
            for (int i = 0; i < 16; ++i) s = fmaf(vsh[b * 17 + i], Msh[b * 264 + i * 16 + j], s);
            wv[q] = s;
        }
        __syncthreads();
        #pragma unroll
        for (int q = 0; q < 2; ++q) { int k = t + q * 256; vsh[(k >> 4) * 17 + (k & 15)] = wv[q]; }
    }
    {
        int i = t >> 4, o = t & 15;
        float lr = 0.f;
        if (o < 10) {
            const float* lp = fl + ((size_t)i * 10 + o) * 16;
            #pragma unroll
            for (int j = 0; j < 16; ++j) lr += lp[j];
        }
        lsh[i * 17 + o] = lr * 0.25f;
    }
    __syncthreads();
    for (int k = t; k < 512; k += 256) {
        int b = k >> 4, o = k & 15;
        if (o < 10) {
            float s = 0.f;
            #pragma unroll
            for (int i = 0; i < 16; ++i) s = fmaf(vsh[b * 17 + i], lsh[i * 17 + o], s);
            out[b * 10 + o] = s;
        }
    }
}

extern "C" void kernel_launch(void* const* d_in, const int* in_sizes, int n_in,
                              void* d_out, int out_size, void* d_ws, size_t ws_size,
                              hipStream_t stream) {
    const float* x   = (const float*)d_in[0];
    const float* l1c = (const float*)d_in[1];
    const float* l1l = (const float*)d_in[2];
    const float* c1c = (const float*)d_in[3];
    const float* c1l = (const float*)d_in[4];
    const float* l2c = (const float*)d_in[5];
    const float* l2l = (const float*)d_in[6];
    const float* c2c = (const float*)d_in[7];
    const float* c2l = (const float*)d_in[8];
    const float* l3c = (const float*)d_in[9];
    const float* l3l = (const float*)d_in[10];
    const float* c3c = (const float*)d_in[11];
    const float* c3l = (const float*)d_in[12];
    const float* fc  = (const float*)d_in[13];
    const float* fl  = (const float*)d_in[14];
    const float* g1  = (const float*)d_in[15];
    const float* b1  = (const float*)d_in[16];
    const float* gc1 = (const float*)d_in[17];
    const float* bc1 = (const float*)d_in[18];
    const float* g2  = (const float*)d_in[19];
    const float* b2  = (const float*)d_in[20];
    const float* g3  = (const float*)d_in[21];
    const float* b3  = (const float*)d_in[22];
    float* ws  = (float*)d_ws;   // needs 29.7 MB
    float* out = (float*)d_out;

    // ---- stage 1 ----
    k_phi1<<<12288, 256, 0, stream>>>(x, ws + W_PHI1L, ws + W_PHI1C);
    k_labRB<<<1440, 256, 0, stream>>>(l1l, c1l, l2l, c2l, l3l, c3l, ws);
    k_fused1<<<1280, 256, 0, stream>>>(ws + W_PHI1L, ws + W_PHI1C, l1c, c1c,
                                       ws + W_LR1L, ws + W_LR1C, ws + W_LY, ws + W_CY);
    k_bn1<<<1280, 64, 0, stream>>>(ws + W_LY, ws + W_CY, g1, b1, gc1, bc1,
                                   ws + W_SCL, ws + W_SHL, ws + W_SCC, ws + W_SHC);
    // ---- stage 2 ----
    k_phi2<<<5120, 256, 0, stream>>>(ws + W_LY, ws + W_CY, ws + W_SCL, ws + W_SHL,
                                     ws + W_SCC, ws + W_SHC, ws + W_PHI2L, ws + W_PHI2C);
    k_fused2<<<128, 256, 0, stream>>>(ws + W_PHI2L, ws + W_PHI2C, l2c, c2c,
                                      ws + W_LR2L, ws + W_LR2C, ws + W_LO2, ws + W_CO2);
    k_bn2<<<64, 64, 0, stream>>>(ws + W_LO2, ws + W_CO2, g2, b2, ws + W_SC2, ws + W_SH2);
    // ---- stage 3 ----
    k_phi3<<<512, 256, 0, stream>>>(ws + W_LO2, ws + W_CO2, ws + W_SC2, ws + W_SH2,
                                    ws + W_PHI3L, ws + W_PHI3C);
    k_fused3<<<32, 256, 0, stream>>>(ws + W_PHI3L, ws + W_PHI3C, l3c, c3c,
                                     ws + W_LR3L, ws + W_LR3C, ws + W_LO3, ws + W_CO3);
    // ---- final ----
    k_bn3_phiF<<<1, 256, 0, stream>>>(ws + W_LO3, ws + W_CO3, g3, b3, ws + W_PHIF);
    k_mpsF_build<<<16, 256, 0, stream>>>(ws + W_PHIF, fc, ws + W_MF);
    k_mpsF_chain<<<1, 256, 0, stream>>>(ws + W_MF, fl, out);
}